// Round 3
// baseline (5460.310 us; speedup 1.0000x reference)
//
#include <hip/hip_runtime.h>

#define B_   4
#define C_   256
#define NH_  8
#define HD_  32
#define NP_  3
#define NL_  4
#define LYR_ 3
#define DFF_ 1024
#define N_   12240          // 96*96 + 48*48 + 24*24 + 12*12
#define M_   (B_*N_)        // 48960

// ---------------------------------------------------------------- concat ----
// x[b,n,c]  = src_li[b,c,s]
// pf[b,n,c] = pos_li[b,c,s] + level_embed[li,c]
__global__ __launch_bounds__(256) void k_concat(
    const float* __restrict__ s0, const float* __restrict__ s1,
    const float* __restrict__ s2, const float* __restrict__ s3,
    const float* __restrict__ p0, const float* __restrict__ p1,
    const float* __restrict__ p2, const float* __restrict__ p3,
    const float* __restrict__ lev, float* __restrict__ x, float* __restrict__ pf)
{
    int idx = blockIdx.x * 256 + threadIdx.x;      // over M_*C_ (exact)
    int c  = idx & (C_ - 1);
    int bn = idx >> 8;
    int n  = bn % N_;
    int b  = bn / N_;
    int li, s, HW; const float *sp, *pp;
    if (n < 9216)       { li = 0; s = n;         HW = 9216; sp = s0; pp = p0; }
    else if (n < 11520) { li = 1; s = n - 9216;  HW = 2304; sp = s1; pp = p1; }
    else if (n < 12096) { li = 2; s = n - 11520; HW = 576;  sp = s2; pp = p2; }
    else                { li = 3; s = n - 12096; HW = 144;  sp = s3; pp = p3; }
    size_t o = (size_t)(b * C_ + c) * HW + s;
    x[idx]  = sp[o];
    pf[idx] = pp[o] + lev[li * C_ + c];
}

// zero value rows where mask set (mask is bool bytes; all-false in practice)
__global__ __launch_bounds__(256) void k_mask(
    float* __restrict__ v,
    const unsigned char* __restrict__ m0, const unsigned char* __restrict__ m1,
    const unsigned char* __restrict__ m2, const unsigned char* __restrict__ m3)
{
    int row = blockIdx.x;                          // over M_
    int n = row % N_, b = row / N_;
    int s, HW; const unsigned char* mp;
    if (n < 9216)       { s = n;         HW = 9216; mp = m0; }
    else if (n < 11520) { s = n - 9216;  HW = 2304; mp = m1; }
    else if (n < 12096) { s = n - 11520; HW = 576;  mp = m2; }
    else                { s = n - 12096; HW = 144;  mp = m3; }
    if (mp[b * HW + s])
        v[(size_t)row * C_ + threadIdx.x] = 0.f;
}

// ------------------------------------------------------------------ GEMM ----
// C[M,N] = (A [+ A2]) [M,K] @ W[K,N] + bias[N]; MODE 0 = plain, 1 = exact GELU
// 64x64 tile, BK=16, 256 threads, 4x4 acc/thread. Rows % 64 == 0, K % 16 == 0.
template <int MODE, bool ADD2>
__global__ __launch_bounds__(256) void k_gemm(
    const float* __restrict__ A, const float* __restrict__ A2,
    const float* __restrict__ W,
    const float* __restrict__ bias, float* __restrict__ Cm,
    int Ndim, int Kdim)
{
    __shared__ float As[16][68];   // [k][m]
    __shared__ float Bs[16][68];   // [k][n]
    const int tid = threadIdx.x;
    const int tx = tid & 15, ty = tid >> 4;
    const int bm = blockIdx.y * 64;
    const int bn = blockIdx.x * 64;

    float acc[4][4] = {};

    for (int k0 = 0; k0 < Kdim; k0 += 16) {
        {   // A tile 64x16, float4 per thread
            int m  = tid >> 2;
            int kk = (tid & 3) * 4;
            size_t o = (size_t)(bm + m) * Kdim + k0 + kk;
            float4 v = *(const float4*)&A[o];
            if (ADD2) {
                float4 v2 = *(const float4*)&A2[o];
                v.x += v2.x; v.y += v2.y; v.z += v2.z; v.w += v2.w;
            }
            As[kk + 0][m] = v.x; As[kk + 1][m] = v.y;
            As[kk + 2][m] = v.z; As[kk + 3][m] = v.w;
        }
        {   // B tile 16x64, float4 per thread (N-guarded)
            int kk = tid >> 4;
            int nn = (tid & 15) * 4;
            float4 v = make_float4(0.f, 0.f, 0.f, 0.f);
            if (bn + nn < Ndim)
                v = *(const float4*)&W[(size_t)(k0 + kk) * Ndim + bn + nn];
            Bs[kk][nn + 0] = v.x; Bs[kk][nn + 1] = v.y;
            Bs[kk][nn + 2] = v.z; Bs[kk][nn + 3] = v.w;
        }
        __syncthreads();
        #pragma unroll
        for (int kk = 0; kk < 16; ++kk) {
            float a0 = As[kk][ty * 4 + 0], a1 = As[kk][ty * 4 + 1];
            float a2 = As[kk][ty * 4 + 2], a3 = As[kk][ty * 4 + 3];
            float b0 = Bs[kk][tx * 4 + 0], b1 = Bs[kk][tx * 4 + 1];
            float b2 = Bs[kk][tx * 4 + 2], b3 = Bs[kk][tx * 4 + 3];
            acc[0][0] += a0 * b0; acc[0][1] += a0 * b1; acc[0][2] += a0 * b2; acc[0][3] += a0 * b3;
            acc[1][0] += a1 * b0; acc[1][1] += a1 * b1; acc[1][2] += a1 * b2; acc[1][3] += a1 * b3;
            acc[2][0] += a2 * b0; acc[2][1] += a2 * b1; acc[2][2] += a2 * b2; acc[2][3] += a2 * b3;
            acc[3][0] += a3 * b0; acc[3][1] += a3 * b1; acc[3][2] += a3 * b2; acc[3][3] += a3 * b3;
        }
        __syncthreads();
    }

    int ncol = bn + tx * 4;
    if (ncol < Ndim) {
        float bx = bias[ncol + 0], by = bias[ncol + 1];
        float bz = bias[ncol + 2], bw = bias[ncol + 3];
        #pragma unroll
        for (int i = 0; i < 4; ++i) {
            int m = bm + ty * 4 + i;
            float4 v = make_float4(acc[i][0] + bx, acc[i][1] + by,
                                   acc[i][2] + bz, acc[i][3] + bw);
            if (MODE == 1) {
                v.x = 0.5f * v.x * (1.f + erff(v.x * 0.70710678118654752f));
                v.y = 0.5f * v.y * (1.f + erff(v.y * 0.70710678118654752f));
                v.z = 0.5f * v.z * (1.f + erff(v.z * 0.70710678118654752f));
                v.w = 0.5f * v.w * (1.f + erff(v.w * 0.70710678118654752f));
            }
            *(float4*)&Cm[(size_t)m * Ndim + ncol] = v;
        }
    }
}

// --------------------------------------------------------------- softmax ----
// in-place softmax over the last-12 of (M_*NH_, 12)
__global__ __launch_bounds__(256) void k_softmax12(float* __restrict__ aw)
{
    int g = blockIdx.x * 256 + threadIdx.x;
    if (g >= M_ * NH_) return;
    float* p = aw + (size_t)g * 12;
    float mx = p[0];
    #pragma unroll
    for (int i = 1; i < 12; ++i) mx = fmaxf(mx, p[i]);
    float s = 0.f, e[12];
    #pragma unroll
    for (int i = 0; i < 12; ++i) { e[i] = __expf(p[i] - mx); s += e[i]; }
    float inv = 1.f / s;
    #pragma unroll
    for (int i = 0; i < 12; ++i) p[i] = e[i] * inv;
}

// -------------------------------------------------------------- sampling ----
// one 32-lane group per (b,n,h); lane = d in [0,32)
__global__ __launch_bounds__(256) void k_sample(
    const float* __restrict__ value, const float* __restrict__ off,
    const float* __restrict__ aw, float* __restrict__ out)
{
    int t = blockIdx.x * 256 + threadIdx.x;
    int gid = t >> 5;                  // (b*N + n)*NH + h
    int d = t & 31;
    if (gid >= M_ * NH_) return;
    int h  = gid & 7;
    int bn = gid >> 3;
    int n  = bn % N_;
    int b  = bn / N_;

    int sr, Wr;
    if (n < 9216)       { sr = n;         Wr = 96; }
    else if (n < 11520) { sr = n - 9216;  Wr = 48; }
    else if (n < 12096) { sr = n - 11520; Wr = 24; }
    else                { sr = n - 12096; Wr = 12; }
    int iy = sr / Wr, ix = sr % Wr;
    float refx = (ix + 0.5f) / Wr;
    float refy = (iy + 0.5f) / Wr;     // square levels: Hr == Wr

    const float* offp = off + (size_t)gid * (NL_ * NP_ * 2);
    const float* awp  = aw  + (size_t)gid * (NL_ * NP_);
    const float* vbase = value + (size_t)b * N_ * C_ + h * HD_ + d;

    float acc = 0.f;
    int s0 = 0;
    #pragma unroll
    for (int li = 0; li < 4; ++li) {
        const int Wl = 96 >> li;       // 96,48,24,12 (square)
        #pragma unroll
        for (int p = 0; p < NP_; ++p) {
            float ox = offp[(li * NP_ + p) * 2 + 0];
            float oy = offp[(li * NP_ + p) * 2 + 1];
            // loc = ref + off/NP * 0.1 * 0.5 = ref + off/60
            float xf = (refx + ox * (1.f / 60.f)) * Wl - 0.5f;
            float yf = (refy + oy * (1.f / 60.f)) * Wl - 0.5f;
            float x0f = floorf(xf), y0f = floorf(yf);
            float wx = xf - x0f, wy = yf - y0f;
            int x0 = (int)x0f, y0 = (int)y0f;
            float a = awp[li * NP_ + p];
            float smp = 0.f;
            #pragma unroll
            for (int dy = 0; dy < 2; ++dy) {
                #pragma unroll
                for (int dx = 0; dx < 2; ++dx) {
                    int yi = y0 + dy, xi = x0 + dx;
                    if (xi >= 0 && xi < Wl && yi >= 0 && yi < Wl) {
                        float wgt = (dy ? wy : 1.f - wy) * (dx ? wx : 1.f - wx);
                        smp += wgt * vbase[(size_t)(s0 + yi * Wl + xi) * C_];
                    }
                }
            }
            acc += a * smp;
        }
        s0 += Wl * Wl;
    }
    out[(size_t)gid * HD_ + d] = acc;
}

// ------------------------------------------------------- residual + LN ------
__global__ __launch_bounds__(256) void k_add_ln(
    const float* __restrict__ xin, const float* __restrict__ r,
    const float* __restrict__ g, const float* __restrict__ bta,
    float* __restrict__ out)
{
    int row = blockIdx.x;
    int c = threadIdx.x;
    size_t o = (size_t)row * C_ + c;
    float v = xin[o] + (r ? r[o] : 0.f);
    float s1 = v, s2 = v * v;
    #pragma unroll
    for (int ofs = 32; ofs > 0; ofs >>= 1) {
        s1 += __shfl_down(s1, ofs);
        s2 += __shfl_down(s2, ofs);
    }
    __shared__ float r1[4], r2[4];
    int wid = threadIdx.x >> 6, lane = threadIdx.x & 63;
    if (lane == 0) { r1[wid] = s1; r2[wid] = s2; }
    __syncthreads();
    float m   = (r1[0] + r1[1] + r1[2] + r1[3]) * (1.f / C_);
    float var = (r2[0] + r2[1] + r2[2] + r2[3]) * (1.f / C_) - m * m;
    float inv = rsqrtf(var + 1e-5f);
    out[o] = (v - m) * inv * g[c] + bta[c];
}

// ---------------------------------------------------------------- launch ----
extern "C" void kernel_launch(void* const* d_in, const int* in_sizes, int n_in,
                              void* d_out, int out_size, void* d_ws, size_t ws_size,
                              hipStream_t stream)
{
    const float* src0 = (const float*)d_in[0];
    const unsigned char* mask0 = (const unsigned char*)d_in[1];
    const float* pos0 = (const float*)d_in[2];
    const float* src1 = (const float*)d_in[3];
    const unsigned char* mask1 = (const unsigned char*)d_in[4];
    const float* pos1 = (const float*)d_in[5];
    const float* src2 = (const float*)d_in[6];
    const unsigned char* mask2 = (const unsigned char*)d_in[7];
    const float* pos2 = (const float*)d_in[8];
    const float* src3 = (const float*)d_in[9];
    const unsigned char* mask3 = (const unsigned char*)d_in[10];
    const float* pos3 = (const float*)d_in[11];
    const float* lev    = (const float*)d_in[12];
    const float* W_off  = (const float*)d_in[13];
    const float* b_off  = (const float*)d_in[14];
    const float* W_attw = (const float*)d_in[15];
    const float* b_attw = (const float*)d_in[16];
    const float* W_val  = (const float*)d_in[17];
    const float* b_val  = (const float*)d_in[18];
    const float* W_out  = (const float*)d_in[19];
    const float* b_out  = (const float*)d_in[20];
    const float* ln1_g  = (const float*)d_in[21];
    const float* ln1_b  = (const float*)d_in[22];
    const float* W_ff1  = (const float*)d_in[23];
    const float* b_ff1  = (const float*)d_in[24];
    const float* W_ff2  = (const float*)d_in[25];
    const float* b_ff2  = (const float*)d_in[26];
    const float* ln2_g  = (const float*)d_in[27];
    const float* ln2_b  = (const float*)d_in[28];
    const float* lnf_g  = (const float*)d_in[29];
    const float* lnf_b  = (const float*)d_in[30];

    // workspace layout, in units of M_ floats (total 1312 units = 245 MiB)
    float* ws = (float*)d_ws;
    auto at = [&](size_t u) { return ws + u * (size_t)M_; };
    float* x    = at(0);      // [0,256)
    float* pf   = at(256);    // [256,512)
    float* val  = at(512);    // [512,768)
    float* msda = at(768);    // [768,1024)
    float* offb = at(1024);   // [1024,1216)
    float* awb  = at(1216);   // [1216,1312)
    float* tmp  = at(1024);   // alias offb/awb (dead when tmp live)
    float* hbuf = at(512);    // alias val+msda (dead during FFN); needs 342 units max

    const int EW = (M_ * C_) / 256;
    const dim3 T(256);

    k_concat<<<EW, T, 0, stream>>>(src0, src1, src2, src3, pos0, pos1, pos2, pos3,
                                   lev, x, pf);

    for (int l = 0; l < LYR_; ++l) {
        // value = x @ W_val + b_val ; mask
        k_gemm<0, false><<<dim3(C_ / 64, M_ / 64), T, 0, stream>>>(
            x, nullptr, W_val + (size_t)l * C_ * C_, b_val + l * C_, val, C_, C_);
        k_mask<<<M_, T, 0, stream>>>(val, mask0, mask1, mask2, mask3);

        // off = (x+pf) @ W_off + b_off  (N = 192)
        k_gemm<0, true><<<dim3(3, M_ / 64), T, 0, stream>>>(
            x, pf, W_off + (size_t)l * C_ * 192, b_off + l * 192, offb, 192, C_);

        // attw logits = (x+pf) @ W_attw + b_attw (N = 96), softmax over 12
        k_gemm<0, true><<<dim3(2, M_ / 64), T, 0, stream>>>(
            x, pf, W_attw + (size_t)l * C_ * 96, b_attw + l * 96, awb, 96, C_);
        k_softmax12<<<(M_ * NH_ + 255) / 256, T, 0, stream>>>(awb);

        // sampling
        k_sample<<<(M_ * NH_ * 32) / 256, T, 0, stream>>>(val, offb, awb, msda);

        // out projection (into tmp; offb/awb now dead)
        k_gemm<0, false><<<dim3(C_ / 64, M_ / 64), T, 0, stream>>>(
            msda, nullptr, W_out + (size_t)l * C_ * C_, b_out + l * C_, tmp, C_, C_);

        // x = LN(x + tmp)
        k_add_ln<<<M_, T, 0, stream>>>(x, tmp, ln1_g + l * C_, ln1_b + l * C_, x);

        // FFN in 3 row-chunks of 16320 rows (255 blocks); hbuf aliases val+msda
        for (int ch = 0; ch < 3; ++ch) {
            const int row0 = ch * 16320;
            // h = gelu(x_chunk @ W_ff1 + b_ff1)  (N = 1024)
            k_gemm<1, false><<<dim3(DFF_ / 64, 255), T, 0, stream>>>(
                x + (size_t)row0 * C_, nullptr,
                W_ff1 + (size_t)l * C_ * DFF_, b_ff1 + l * DFF_, hbuf, DFF_, C_);
            // tmp_chunk = h @ W_ff2 + b_ff2  (K = 1024)
            k_gemm<0, false><<<dim3(C_ / 64, 255), T, 0, stream>>>(
                hbuf, nullptr,
                W_ff2 + (size_t)l * DFF_ * C_, b_ff2 + l * C_,
                tmp + (size_t)row0 * C_, C_, DFF_);
        }

        // x = LN(x + tmp)
        k_add_ln<<<M_, T, 0, stream>>>(x, tmp, ln2_g + l * C_, ln2_b + l * C_, x);
    }

    // final LN -> d_out
    k_add_ln<<<M_, T, 0, stream>>>(x, nullptr, lnf_g, lnf_b, (float*)d_out);
}

// Round 4
// 2545.847 us; speedup vs baseline: 2.1448x; 2.1448x over previous
//
#include <hip/hip_runtime.h>

#define B_   4
#define C_   256
#define NH_  8
#define HD_  32
#define NP_  3
#define NL_  4
#define LYR_ 3
#define DFF_ 1024
#define N_   12240          // 96*96 + 48*48 + 24*24 + 12*12
#define M_   (B_*N_)        // 48960
#define MP_  49152          // rows padded to 384*128 for BM=128 tiles
#define LT_  729088         // per-layer elems in transposed weight block

typedef __attribute__((ext_vector_type(8))) short short8;
typedef __attribute__((ext_vector_type(4))) float f32x4;

__device__ __forceinline__ unsigned short f2bf(float f) {
    union { float f; unsigned u; } v; v.f = f;
    unsigned r = (v.u + 0x7fffu + ((v.u >> 16) & 1u)) >> 16;
    return (unsigned short)r;
}
__device__ __forceinline__ float bf2f(unsigned short h) {
    union { unsigned u; float f; } v; v.u = ((unsigned)h) << 16;
    return v.f;
}

// ---------------------------------------------------------------- concat ----
__global__ __launch_bounds__(256) void k_concat(
    const float* __restrict__ s0, const float* __restrict__ s1,
    const float* __restrict__ s2, const float* __restrict__ s3,
    const float* __restrict__ p0, const float* __restrict__ p1,
    const float* __restrict__ p2, const float* __restrict__ p3,
    const float* __restrict__ lev, float* __restrict__ x, float* __restrict__ pf)
{
    int idx = blockIdx.x * 256 + threadIdx.x;      // over M_*C_ (exact)
    int c  = idx & (C_ - 1);
    int bn = idx >> 8;
    int n  = bn % N_;
    int b  = bn / N_;
    int li, s, HW; const float *sp, *pp;
    if (n < 9216)       { li = 0; s = n;         HW = 9216; sp = s0; pp = p0; }
    else if (n < 11520) { li = 1; s = n - 9216;  HW = 2304; sp = s1; pp = p1; }
    else if (n < 12096) { li = 2; s = n - 11520; HW = 576;  sp = s2; pp = p2; }
    else                { li = 3; s = n - 12096; HW = 144;  sp = s3; pp = p3; }
    size_t o = (size_t)(b * C_ + c) * HW + s;
    x[idx]  = sp[o];
    pf[idx] = pp[o] + lev[li * C_ + c];
}

// ---------------------------------------------------------------- mask ------
__global__ __launch_bounds__(256) void k_mask(
    float* __restrict__ v,
    const unsigned char* __restrict__ m0, const unsigned char* __restrict__ m1,
    const unsigned char* __restrict__ m2, const unsigned char* __restrict__ m3)
{
    int row = blockIdx.x;                          // over M_
    int n = row % N_, b = row / N_;
    int s, HW; const unsigned char* mp;
    if (n < 9216)       { s = n;         HW = 9216; mp = m0; }
    else if (n < 11520) { s = n - 9216;  HW = 2304; mp = m1; }
    else if (n < 12096) { s = n - 11520; HW = 576;  mp = m2; }
    else                { s = n - 12096; HW = 144;  mp = m3; }
    if (mp[b * HW + s])
        v[(size_t)row * C_ + threadIdx.x] = 0.f;
}

// ------------------------------------------------------- weight split/T -----
// W[LYR][K][N] (row-major, per-layer stride = K*N) -> Th/Tl[LYR][N][K] bf16
__global__ __launch_bounds__(256) void k_split(
    const float* __restrict__ W, unsigned short* __restrict__ Th,
    unsigned short* __restrict__ Tl, int K, int N)
{
    int per = K * N;
    int idx = blockIdx.x * 256 + threadIdx.x;
    if (idx >= LYR_ * per) return;
    int l = idx / per, r = idx - l * per;
    int k = r / N, n = r - k * N;
    float v = W[idx];
    unsigned short h = f2bf(v);
    unsigned short lo = f2bf(v - bf2f(h));
    size_t o = (size_t)l * LT_ + (size_t)n * K + k;
    Th[o] = h; Tl[o] = lo;
}

// --------------------------------------------------------- MFMA GEMM --------
// C[rows][Ndim] = (A [+A2])[rows][K] @ T[Ndim][K]^T + bias, split-bf16 (3 MFMA)
// block 128x128, 4 waves of 64x64, BK=64. Kdim % 64 == 0, rows % 128 == 0.
__device__ __forceinline__ int swz(int row, int bcol) {
    return row * 128 + (bcol ^ ((row & 7) << 4));   // bytes
}

template <int MODE, bool ADD2>
__global__ __launch_bounds__(256) void k_mgemm(
    const float* __restrict__ A, const float* __restrict__ A2,
    const unsigned short* __restrict__ Bh, const unsigned short* __restrict__ Bl,
    const float* __restrict__ bias, const float* __restrict__ bias2, int bsplit,
    float* __restrict__ Cm, int Ndim, int Kdim)
{
    __shared__ __align__(16) unsigned short Ahs[128 * 64];
    __shared__ __align__(16) unsigned short Als[128 * 64];
    __shared__ __align__(16) unsigned short Bhs[128 * 64];
    __shared__ __align__(16) unsigned short Bls[128 * 64];

    const int tid = threadIdx.x;
    const int bm = blockIdx.y * 128;
    const int bn = blockIdx.x * 128;
    const int w  = tid >> 6, lane = tid & 63;
    const int wr = w >> 1, wc = w & 1;
    const int lm = lane & 15, lg = lane >> 4;

    const int srow = tid >> 1;              // staging row 0..127
    const int sbc  = (tid & 1) * 64;        // staging byte-col base (0 or 64)

    f32x4 acc[4][4] = {};

    for (int k0 = 0; k0 < Kdim; k0 += 64) {
        {   // stage A (+A2), split hi/lo
            const float* Ap  = A  + (size_t)(bm + srow) * Kdim + k0 + (sbc >> 1);
            const float* A2p = A2 + (size_t)(bm + srow) * Kdim + k0 + (sbc >> 1);
            #pragma unroll
            for (int q = 0; q < 4; ++q) {
                float4 v0 = *(const float4*)(Ap + q * 8);
                float4 v1 = *(const float4*)(Ap + q * 8 + 4);
                if (ADD2) {
                    float4 u0 = *(const float4*)(A2p + q * 8);
                    float4 u1 = *(const float4*)(A2p + q * 8 + 4);
                    v0.x += u0.x; v0.y += u0.y; v0.z += u0.z; v0.w += u0.w;
                    v1.x += u1.x; v1.y += u1.y; v1.z += u1.z; v1.w += u1.w;
                }
                float f[8] = {v0.x, v0.y, v0.z, v0.w, v1.x, v1.y, v1.z, v1.w};
                short8 hv, lv;
                #pragma unroll
                for (int j = 0; j < 8; ++j) {
                    unsigned short h = f2bf(f[j]);
                    hv[j] = (short)h;
                    lv[j] = (short)f2bf(f[j] - bf2f(h));
                }
                int o = swz(srow, sbc + q * 16) >> 1;
                *(short8*)&Ahs[o] = hv;
                *(short8*)&Als[o] = lv;
            }
        }
        {   // stage B (pre-split bf16, [N][K] rows)
            int ng = bn + srow;
            bool ok = ng < Ndim;
            const unsigned short* bhp = Bh + (size_t)ng * Kdim + k0 + (sbc >> 1);
            const unsigned short* blp = Bl + (size_t)ng * Kdim + k0 + (sbc >> 1);
            #pragma unroll
            for (int q = 0; q < 4; ++q) {
                short8 hv = {}, lv = {};
                if (ok) {
                    hv = *(const short8*)(bhp + q * 8);
                    lv = *(const short8*)(blp + q * 8);
                }
                int o = swz(srow, sbc + q * 16) >> 1;
                *(short8*)&Bhs[o] = hv;
                *(short8*)&Bls[o] = lv;
            }
        }
        __syncthreads();
        #pragma unroll
        for (int ks = 0; ks < 2; ++ks) {
            const int cb = ks * 64 + lg * 16;
            short8 ah[4], al[4], bh[4], bl[4];
            #pragma unroll
            for (int i = 0; i < 4; ++i) {
                int o = swz(wr * 64 + i * 16 + lm, cb) >> 1;
                ah[i] = *(const short8*)&Ahs[o];
                al[i] = *(const short8*)&Als[o];
            }
            #pragma unroll
            for (int j = 0; j < 4; ++j) {
                int o = swz(wc * 64 + j * 16 + lm, cb) >> 1;
                bh[j] = *(const short8*)&Bhs[o];
                bl[j] = *(const short8*)&Bls[o];
            }
            #pragma unroll
            for (int i = 0; i < 4; ++i)
                #pragma unroll
                for (int j = 0; j < 4; ++j) {
                    acc[i][j] = __builtin_amdgcn_mfma_f32_16x16x32_bf16(al[i], bh[j], acc[i][j], 0, 0, 0);
                    acc[i][j] = __builtin_amdgcn_mfma_f32_16x16x32_bf16(ah[i], bl[j], acc[i][j], 0, 0, 0);
                    acc[i][j] = __builtin_amdgcn_mfma_f32_16x16x32_bf16(ah[i], bh[j], acc[i][j], 0, 0, 0);
                }
        }
        __syncthreads();
    }

    // epilogue: bias (+GELU) + store. C/D: col = lane&15, row = (lane>>4)*4+p
    #pragma unroll
    for (int j = 0; j < 4; ++j) {
        int col = bn + wc * 64 + j * 16 + lm;
        if (col < Ndim) {
            float bb = (col < bsplit) ? bias[col] : bias2[col - bsplit];
            #pragma unroll
            for (int i = 0; i < 4; ++i) {
                #pragma unroll
                for (int p = 0; p < 4; ++p) {
                    int row = bm + wr * 64 + i * 16 + lg * 4 + p;
                    float v = acc[i][j][p] + bb;
                    if (MODE == 1)
                        v = 0.5f * v * (1.f + erff(v * 0.70710678118654752f));
                    Cm[(size_t)row * Ndim + col] = v;
                }
            }
        }
    }
}

// -------------------------------------------------------------- sampling ----
// 8 lanes per (b,n,h), lane handles float4 of d; softmax over 12 fused in.
// comb[row][288]: cols 0..191 = offsets (h*24 + (li*NP+p)*2), 192..287 = logits.
__global__ __launch_bounds__(256) void k_sample(
    const float* __restrict__ value, const float* __restrict__ comb,
    float* __restrict__ out)
{
    int t = blockIdx.x * 256 + threadIdx.x;        // M_*NH_*8 exact
    int gid = t >> 3, q4 = t & 3 * 2 + (t & 7);    // placeholder (fixed below)
    gid = t >> 3; q4 = t & 7;
    int h  = gid & 7;
    int bn = gid >> 3;
    int n  = bn % N_;
    int b  = bn / N_;

    int sr, Wr;
    if (n < 9216)       { sr = n;         Wr = 96; }
    else if (n < 11520) { sr = n - 9216;  Wr = 48; }
    else if (n < 12096) { sr = n - 11520; Wr = 24; }
    else                { sr = n - 12096; Wr = 12; }
    int iy = sr / Wr, ix = sr % Wr;
    float refx = (ix + 0.5f) / Wr;
    float refy = (iy + 0.5f) / Wr;

    const float* rowp = comb + (size_t)bn * 288;
    const float* offp = rowp + h * 24;
    const float* lgp  = rowp + 192 + h * 12;

    float lv[12];
    float mx = lgp[0];
    lv[0] = mx;
    #pragma unroll
    for (int i = 1; i < 12; ++i) { lv[i] = lgp[i]; mx = fmaxf(mx, lv[i]); }
    float ssum = 0.f;
    #pragma unroll
    for (int i = 0; i < 12; ++i) { lv[i] = __expf(lv[i] - mx); ssum += lv[i]; }
    float sinv = 1.f / ssum;

    const float* vbase = value + ((size_t)b * N_) * C_ + h * HD_ + q4 * 4;

    float4 acc = make_float4(0.f, 0.f, 0.f, 0.f);
    int s0 = 0;
    #pragma unroll
    for (int li = 0; li < 4; ++li) {
        const int Wl = 96 >> li;
        #pragma unroll
        for (int p = 0; p < NP_; ++p) {
            float ox = offp[(li * NP_ + p) * 2 + 0];
            float oy = offp[(li * NP_ + p) * 2 + 1];
            float xf = (refx + ox * (1.f / 60.f)) * Wl - 0.5f;
            float yf = (refy + oy * (1.f / 60.f)) * Wl - 0.5f;
            float x0f = floorf(xf), y0f = floorf(yf);
            float wx = xf - x0f, wy = yf - y0f;
            int x0 = (int)x0f, y0 = (int)y0f;
            float a = lv[li * NP_ + p] * sinv;
            #pragma unroll
            for (int dy = 0; dy < 2; ++dy) {
                #pragma unroll
                for (int dx = 0; dx < 2; ++dx) {
                    int yi = y0 + dy, xi = x0 + dx;
                    if (xi >= 0 && xi < Wl && yi >= 0 && yi < Wl) {
                        float wgt = a * (dy ? wy : 1.f - wy) * (dx ? wx : 1.f - wx);
                        float4 v = *(const float4*)(vbase + (size_t)(s0 + yi * Wl + xi) * C_);
                        acc.x += wgt * v.x; acc.y += wgt * v.y;
                        acc.z += wgt * v.z; acc.w += wgt * v.w;
                    }
                }
            }
        }
        s0 += Wl * Wl;
    }
    *(float4*)(out + (size_t)gid * HD_ + q4 * 4) = acc;
}

// ------------------------------------------------------- residual + LN ------
__global__ __launch_bounds__(256) void k_add_ln(
    const float* __restrict__ xin, const float* __restrict__ r,
    const float* __restrict__ g, const float* __restrict__ bta,
    float* __restrict__ out)
{
    int row = blockIdx.x;
    int c = threadIdx.x;
    size_t o = (size_t)row * C_ + c;
    float v = xin[o] + (r ? r[o] : 0.f);
    float s1 = v, s2 = v * v;
    #pragma unroll
    for (int ofs = 32; ofs > 0; ofs >>= 1) {
        s1 += __shfl_down(s1, ofs);
        s2 += __shfl_down(s2, ofs);
    }
    __shared__ float r1[4], r2[4];
    int wid = threadIdx.x >> 6, lane = threadIdx.x & 63;
    if (lane == 0) { r1[wid] = s1; r2[wid] = s2; }
    __syncthreads();
    float m   = (r1[0] + r1[1] + r1[2] + r1[3]) * (1.f / C_);
    float var = (r2[0] + r2[1] + r2[2] + r2[3]) * (1.f / C_) - m * m;
    float inv = rsqrtf(var + 1e-5f);
    out[o] = (v - m) * inv * g[c] + bta[c];
}

// ---------------------------------------------------------------- launch ----
extern "C" void kernel_launch(void* const* d_in, const int* in_sizes, int n_in,
                              void* d_out, int out_size, void* d_ws, size_t ws_size,
                              hipStream_t stream)
{
    const float* src0 = (const float*)d_in[0];
    const unsigned char* mask0 = (const unsigned char*)d_in[1];
    const float* pos0 = (const float*)d_in[2];
    const float* src1 = (const float*)d_in[3];
    const unsigned char* mask1 = (const unsigned char*)d_in[4];
    const float* pos1 = (const float*)d_in[5];
    const float* src2 = (const float*)d_in[6];
    const unsigned char* mask2 = (const unsigned char*)d_in[7];
    const float* pos2 = (const float*)d_in[8];
    const float* src3 = (const float*)d_in[9];
    const unsigned char* mask3 = (const unsigned char*)d_in[10];
    const float* pos3 = (const float*)d_in[11];
    const float* lev    = (const float*)d_in[12];
    const float* W_off  = (const float*)d_in[13];
    const float* b_off  = (const float*)d_in[14];
    const float* W_attw = (const float*)d_in[15];
    const float* b_attw = (const float*)d_in[16];
    const float* W_val  = (const float*)d_in[17];
    const float* b_val  = (const float*)d_in[18];
    const float* W_out  = (const float*)d_in[19];
    const float* b_out  = (const float*)d_in[20];
    const float* ln1_g  = (const float*)d_in[21];
    const float* ln1_b  = (const float*)d_in[22];
    const float* W_ff1  = (const float*)d_in[23];
    const float* b_ff1  = (const float*)d_in[24];
    const float* W_ff2  = (const float*)d_in[25];
    const float* b_ff2  = (const float*)d_in[26];
    const float* ln2_g  = (const float*)d_in[27];
    const float* ln2_b  = (const float*)d_in[28];
    const float* lnf_g  = (const float*)d_in[29];
    const float* lnf_b  = (const float*)d_in[30];

    // ---- workspace: activations in units of MP_ floats, then split weights
    float* ws = (float*)d_ws;
    auto at = [&](size_t u) { return ws + u * (size_t)MP_; };
    float* x    = at(0);      // [0,256)
    float* pf   = at(256);    // [256,512)
    float* val  = at(512);    // [512,768)
    float* msda = at(768);    // [768,1024)
    float* comb = at(1024);   // [1024,1312): offsets(192) + logits(96)
    float* tmp  = at(1024);   // alias comb (dead once sampling done)
    float* hbuf = at(512);    // alias val+msda during FFN (needs 342 < 512)

    unsigned short* Wh = (unsigned short*)(ws + (size_t)1312 * MP_);
    unsigned short* Wl = Wh + (size_t)LYR_ * LT_;
    // per-layer type offsets in transposed block:
    const size_t OF_VAL = 0, OF_CMB = 65536, OF_ATT = 114688,
                 OF_OUT = 139264, OF_F1 = 204800, OF_F2 = 466944;

    const dim3 T(256);
    const int BIG = 1 << 30;

    // ---- weight split+transpose (every call; ~8.4MB read)
    k_split<<<(LYR_*65536 + 255)/256, T, 0, stream>>>(W_val,  Wh + OF_VAL, Wl + OF_VAL, 256, 256);
    k_split<<<(LYR_*49152 + 255)/256, T, 0, stream>>>(W_off,  Wh + OF_CMB, Wl + OF_CMB, 256, 192);
    k_split<<<(LYR_*24576 + 255)/256, T, 0, stream>>>(W_attw, Wh + OF_ATT, Wl + OF_ATT, 256, 96);
    k_split<<<(LYR_*65536 + 255)/256, T, 0, stream>>>(W_out,  Wh + OF_OUT, Wl + OF_OUT, 256, 256);
    k_split<<<(LYR_*262144 + 255)/256, T, 0, stream>>>(W_ff1, Wh + OF_F1,  Wl + OF_F1,  256, 1024);
    k_split<<<(LYR_*262144 + 255)/256, T, 0, stream>>>(W_ff2, Wh + OF_F2,  Wl + OF_F2,  1024, 256);

    k_concat<<<(M_*C_)/256, T, 0, stream>>>(src0, src1, src2, src3,
                                            pos0, pos1, pos2, pos3, lev, x, pf);

    for (int l = 0; l < LYR_; ++l) {
        const size_t lw = (size_t)l * LT_;

        // value = x @ W_val^T + b_val
        k_mgemm<0, false><<<dim3(2, MP_/128), T, 0, stream>>>(
            x, x, Wh + lw + OF_VAL, Wl + lw + OF_VAL,
            b_val + l*C_, b_val + l*C_, BIG, val, 256, 256);
        k_mask<<<M_, T, 0, stream>>>(val, mask0, mask1, mask2, mask3);

        // comb = (x+pf) @ [W_off|W_attw]^T + [b_off|b_attw]  (N = 288)
        k_mgemm<0, true><<<dim3(3, MP_/128), T, 0, stream>>>(
            x, pf, Wh + lw + OF_CMB, Wl + lw + OF_CMB,
            b_off + l*192, b_attw + l*96, 192, comb, 288, 256);

        // sampling (softmax fused)
        k_sample<<<(M_*NH_*8)/256, T, 0, stream>>>(val, comb, msda);

        // out projection (into tmp; comb dead now)
        k_mgemm<0, false><<<dim3(2, MP_/128), T, 0, stream>>>(
            msda, msda, Wh + lw + OF_OUT, Wl + lw + OF_OUT,
            b_out + l*C_, b_out + l*C_, BIG, tmp, 256, 256);

        // x = LN(x + tmp)
        k_add_ln<<<M_, T, 0, stream>>>(x, tmp, ln1_g + l*C_, ln1_b + l*C_, x);

        // FFN in 3 chunks of 16384 rows; hbuf aliases val+msda
        for (int ch = 0; ch < 3; ++ch) {
            const size_t row0 = (size_t)ch * 16384;
            k_mgemm<1, false><<<dim3(8, 128), T, 0, stream>>>(
                x + row0*C_, x + row0*C_, Wh + lw + OF_F1, Wl + lw + OF_F1,
                b_ff1 + l*DFF_, b_ff1 + l*DFF_, BIG, hbuf, 1024, 256);
            k_mgemm<0, false><<<dim3(2, 128), T, 0, stream>>>(
                hbuf, hbuf, Wh + lw + OF_F2, Wl + lw + OF_F2,
                b_ff2 + l*C_, b_ff2 + l*C_, BIG, tmp + row0*C_, 256, 1024);
        }

        // x = LN(x + tmp)
        k_add_ln<<<M_, T, 0, stream>>>(x, tmp, ln2_g + l*C_, ln2_b + l*C_, x);
    }

    k_add_ln<<<M_, T, 0, stream>>>(x, nullptr, lnf_g, lnf_b, (float*)d_out);
}

// Round 5
// 2401.731 us; speedup vs baseline: 2.2735x; 1.0600x over previous
//
#include <hip/hip_runtime.h>

#define B_   4
#define C_   256
#define NH_  8
#define HD_  32
#define NP_  3
#define NL_  4
#define LYR_ 3
#define DFF_ 1024
#define N_   12240          // 96*96 + 48*48 + 24*24 + 12*12
#define M_   (B_*N_)        // 48960
#define MP_  49152          // rows padded to 384*128 for BM=128 tiles
#define LT_  729088         // per-layer elems in transposed weight block

typedef __attribute__((ext_vector_type(8))) short short8;
typedef __attribute__((ext_vector_type(4))) float f32x4;

__device__ __forceinline__ unsigned short f2bf(float f) {
    union { float f; unsigned u; } v; v.f = f;
    unsigned r = (v.u + 0x7fffu + ((v.u >> 16) & 1u)) >> 16;
    return (unsigned short)r;
}
__device__ __forceinline__ float bf2f(unsigned short h) {
    union { unsigned u; float f; } v; v.u = ((unsigned)h) << 16;
    return v.f;
}

// ------------------------------------------------- concat (LDS transpose) ---
// src[b,c,s] -> xh/xl[b,n,c] (split), pf[b,n,c] = pos + lev. 32x32 tiles.
__global__ __launch_bounds__(256) void k_concat_t(
    const float* __restrict__ s0, const float* __restrict__ s1,
    const float* __restrict__ s2, const float* __restrict__ s3,
    const float* __restrict__ p0, const float* __restrict__ p1,
    const float* __restrict__ p2, const float* __restrict__ p3,
    const float* __restrict__ lev,
    unsigned short* __restrict__ xh, unsigned short* __restrict__ xl,
    float* __restrict__ pf)
{
    const int z = blockIdx.z;
    const int b = z >> 2, li = z & 3;
    const int HWs[4]  = {9216, 2304, 576, 144};
    const int offs[4] = {0, 9216, 11520, 12096};
    const int HW = HWs[li];
    const int s0i = blockIdx.x * 32;
    if (s0i >= HW) return;
    const int ct = blockIdx.y * 32;
    const float* sp = (li == 0) ? s0 : (li == 1) ? s1 : (li == 2) ? s2 : s3;
    const float* pp = (li == 0) ? p0 : (li == 1) ? p1 : (li == 2) ? p2 : p3;

    __shared__ float tsx[32][33], tsp[32][33];
    const int tid = threadIdx.x;
    const int tc  = tid & 31;          // s-local on read, c-local on write
    const int tr0 = tid >> 5;          // 0..7

    #pragma unroll
    for (int r = 0; r < 4; ++r) {
        int cl = tr0 + r * 8;          // c within tile
        int s  = s0i + tc;
        float vx = 0.f, vp = 0.f;
        if (s < HW) {
            size_t o = (size_t)(b * C_ + ct + cl) * HW + s;
            vx = sp[o]; vp = pp[o];
        }
        tsx[cl][tc] = vx; tsp[cl][tc] = vp;
    }
    __syncthreads();
    const float lv = lev[li * C_ + ct + tc];
    #pragma unroll
    for (int r = 0; r < 4; ++r) {
        int sl = tr0 + r * 8;          // s within tile
        int s  = s0i + sl;
        if (s < HW) {
            int row = b * N_ + offs[li] + s;
            size_t o = (size_t)row * C_ + ct + tc;
            float vx = tsx[tc][sl];
            unsigned short h = f2bf(vx);
            xh[o] = h;
            xl[o] = f2bf(vx - bf2f(h));
            pf[o] = tsp[tc][sl] + lv;
        }
    }
}

// ---------------------------------------------------------------- mask ------
__global__ __launch_bounds__(256) void k_mask(
    float* __restrict__ v,
    const unsigned char* __restrict__ m0, const unsigned char* __restrict__ m1,
    const unsigned char* __restrict__ m2, const unsigned char* __restrict__ m3)
{
    int row = blockIdx.x;
    int n = row % N_, b = row / N_;
    int s, HW; const unsigned char* mp;
    if (n < 9216)       { s = n;         HW = 9216; mp = m0; }
    else if (n < 11520) { s = n - 9216;  HW = 2304; mp = m1; }
    else if (n < 12096) { s = n - 11520; HW = 576;  mp = m2; }
    else                { s = n - 12096; HW = 144;  mp = m3; }
    if (mp[b * HW + s])
        v[(size_t)row * C_ + threadIdx.x] = 0.f;
}

// ------------------------------------------------------- weight split/T -----
// W[LYR][K][N] -> Th/Tl[LYR][N][K] bf16 hi/lo
__global__ __launch_bounds__(256) void k_split(
    const float* __restrict__ W, unsigned short* __restrict__ Th,
    unsigned short* __restrict__ Tl, int K, int N)
{
    int per = K * N;
    int idx = blockIdx.x * 256 + threadIdx.x;
    if (idx >= LYR_ * per) return;
    int l = idx / per, r = idx - l * per;
    int k = r / N, n = r - k * N;
    float v = W[idx];
    unsigned short h = f2bf(v);
    unsigned short lo = f2bf(v - bf2f(h));
    size_t o = (size_t)l * LT_ + (size_t)n * K + k;
    Th[o] = h; Tl[o] = lo;
}

// --------------------------------------------------------- MFMA GEMM --------
// C[rows][Ndim] = A[rows][K] @ T[Ndim][K]^T + bias, split-bf16 (3 MFMA).
// AKIND 0: A pre-split (Ah,Al). AKIND 1: A = (Ah+Al) + A2f, split at stage.
// MODE 0: fp32 store to Cf. MODE 1: exact GELU + split store to Ch/Cl.
__device__ __forceinline__ int swz(int row, int bcol) {
    return row * 128 + (bcol ^ ((row & 7) << 4));   // bytes
}

template <int MODE, int AKIND>
__global__ __launch_bounds__(256) void k_mgemm(
    const unsigned short* __restrict__ Ah, const unsigned short* __restrict__ Al,
    const float* __restrict__ A2f,
    const unsigned short* __restrict__ Bh, const unsigned short* __restrict__ Bl,
    const float* __restrict__ bias, const float* __restrict__ bias2, int bsplit,
    float* __restrict__ Cf, unsigned short* __restrict__ Ch,
    unsigned short* __restrict__ Cl, int Ndim, int Kdim)
{
    __shared__ __align__(16) unsigned short Ahs[128 * 64];
    __shared__ __align__(16) unsigned short Als[128 * 64];
    __shared__ __align__(16) unsigned short Bhs[128 * 64];
    __shared__ __align__(16) unsigned short Bls[128 * 64];

    const int tid = threadIdx.x;
    const int bm = blockIdx.y * 128;
    const int bn = blockIdx.x * 128;
    const int w  = tid >> 6, lane = tid & 63;
    const int wr = w >> 1, wc = w & 1;
    const int lm = lane & 15, lg = lane >> 4;

    const int srow = tid >> 1;              // staging row 0..127
    const int sbc  = (tid & 1) * 64;        // staging byte-col base (0 or 64)

    f32x4 acc[4][4] = {};

    for (int k0 = 0; k0 < Kdim; k0 += 64) {
        {   // stage A
            const unsigned short* ahp = Ah + (size_t)(bm + srow) * Kdim + k0 + (sbc >> 1);
            const unsigned short* alp = Al + (size_t)(bm + srow) * Kdim + k0 + (sbc >> 1);
            if (AKIND == 0) {
                #pragma unroll
                for (int q = 0; q < 4; ++q) {
                    short8 hv = *(const short8*)(ahp + q * 8);
                    short8 lv = *(const short8*)(alp + q * 8);
                    int o = swz(srow, sbc + q * 16) >> 1;
                    *(short8*)&Ahs[o] = hv;
                    *(short8*)&Als[o] = lv;
                }
            } else {
                const float* a2p = A2f + (size_t)(bm + srow) * Kdim + k0 + (sbc >> 1);
                #pragma unroll
                for (int q = 0; q < 4; ++q) {
                    short8 h8 = *(const short8*)(ahp + q * 8);
                    short8 l8 = *(const short8*)(alp + q * 8);
                    float4 u0 = *(const float4*)(a2p + q * 8);
                    float4 u1 = *(const float4*)(a2p + q * 8 + 4);
                    float f[8] = {u0.x, u0.y, u0.z, u0.w, u1.x, u1.y, u1.z, u1.w};
                    short8 hv, lv;
                    #pragma unroll
                    for (int j = 0; j < 8; ++j) {
                        float v = f[j] + bf2f((unsigned short)h8[j]) + bf2f((unsigned short)l8[j]);
                        unsigned short h = f2bf(v);
                        hv[j] = (short)h;
                        lv[j] = (short)f2bf(v - bf2f(h));
                    }
                    int o = swz(srow, sbc + q * 16) >> 1;
                    *(short8*)&Ahs[o] = hv;
                    *(short8*)&Als[o] = lv;
                }
            }
        }
        {   // stage B (pre-split bf16, [N][K] rows)
            int ng = bn + srow;
            bool ok = ng < Ndim;
            const unsigned short* bhp = Bh + (size_t)ng * Kdim + k0 + (sbc >> 1);
            const unsigned short* blp = Bl + (size_t)ng * Kdim + k0 + (sbc >> 1);
            #pragma unroll
            for (int q = 0; q < 4; ++q) {
                short8 hv = {}, lv = {};
                if (ok) {
                    hv = *(const short8*)(bhp + q * 8);
                    lv = *(const short8*)(blp + q * 8);
                }
                int o = swz(srow, sbc + q * 16) >> 1;
                *(short8*)&Bhs[o] = hv;
                *(short8*)&Bls[o] = lv;
            }
        }
        __syncthreads();
        #pragma unroll
        for (int ks = 0; ks < 2; ++ks) {
            const int cb = ks * 64 + lg * 16;
            short8 ah[4], al[4], bh[4], bl[4];
            #pragma unroll
            for (int i = 0; i < 4; ++i) {
                int o = swz(wr * 64 + i * 16 + lm, cb) >> 1;
                ah[i] = *(const short8*)&Ahs[o];
                al[i] = *(const short8*)&Als[o];
            }
            #pragma unroll
            for (int j = 0; j < 4; ++j) {
                int o = swz(wc * 64 + j * 16 + lm, cb) >> 1;
                bh[j] = *(const short8*)&Bhs[o];
                bl[j] = *(const short8*)&Bls[o];
            }
            #pragma unroll
            for (int i = 0; i < 4; ++i)
                #pragma unroll
                for (int j = 0; j < 4; ++j) {
                    acc[i][j] = __builtin_amdgcn_mfma_f32_16x16x32_bf16(al[i], bh[j], acc[i][j], 0, 0, 0);
                    acc[i][j] = __builtin_amdgcn_mfma_f32_16x16x32_bf16(ah[i], bl[j], acc[i][j], 0, 0, 0);
                    acc[i][j] = __builtin_amdgcn_mfma_f32_16x16x32_bf16(ah[i], bh[j], acc[i][j], 0, 0, 0);
                }
        }
        __syncthreads();
    }

    // epilogue. C/D: col = lane&15, row = (lane>>4)*4 + p
    #pragma unroll
    for (int j = 0; j < 4; ++j) {
        int col = bn + wc * 64 + j * 16 + lm;
        if (col < Ndim) {
            float bb = (col < bsplit) ? bias[col] : bias2[col - bsplit];
            #pragma unroll
            for (int i = 0; i < 4; ++i) {
                #pragma unroll
                for (int p = 0; p < 4; ++p) {
                    int row = bm + wr * 64 + i * 16 + lg * 4 + p;
                    float v = acc[i][j][p] + bb;
                    if (MODE == 1) {
                        v = 0.5f * v * (1.f + erff(v * 0.70710678118654752f));
                        unsigned short h = f2bf(v);
                        Ch[(size_t)row * Ndim + col] = h;
                        Cl[(size_t)row * Ndim + col] = f2bf(v - bf2f(h));
                    } else {
                        Cf[(size_t)row * Ndim + col] = v;
                    }
                }
            }
        }
    }
}

// -------------------------------------------------------------- sampling ----
// 8 lanes per (b,n,h), lane handles float4 of d; softmax over 12 fused.
// comb[row][288]: 0..191 = offsets (h*24 + (li*NP+p)*2), 192..287 = logits.
// Output written pre-split to msh/msl (bf16 hi/lo).
__global__ __launch_bounds__(256) void k_sample(
    const float* __restrict__ value, const float* __restrict__ comb,
    unsigned short* __restrict__ msh, unsigned short* __restrict__ msl)
{
    int t = blockIdx.x * 256 + threadIdx.x;        // M_*NH_*8 exact
    int gid = t >> 3;
    int q4  = t & 7;
    int h  = gid & 7;
    int bn = gid >> 3;
    int n  = bn % N_;
    int b  = bn / N_;

    int sr, Wr;
    if (n < 9216)       { sr = n;         Wr = 96; }
    else if (n < 11520) { sr = n - 9216;  Wr = 48; }
    else if (n < 12096) { sr = n - 11520; Wr = 24; }
    else                { sr = n - 12096; Wr = 12; }
    int iy = sr / Wr, ix = sr % Wr;
    float refx = (ix + 0.5f) / Wr;
    float refy = (iy + 0.5f) / Wr;

    const float* rowp = comb + (size_t)bn * 288;
    const float* offp = rowp + h * 24;
    const float* lgp  = rowp + 192 + h * 12;

    float lv[12];
    float mx = lgp[0];
    lv[0] = mx;
    #pragma unroll
    for (int i = 1; i < 12; ++i) { lv[i] = lgp[i]; mx = fmaxf(mx, lv[i]); }
    float ssum = 0.f;
    #pragma unroll
    for (int i = 0; i < 12; ++i) { lv[i] = __expf(lv[i] - mx); ssum += lv[i]; }
    float sinv = 1.f / ssum;

    const float* vbase = value + ((size_t)b * N_) * C_ + h * HD_ + q4 * 4;

    float4 acc = make_float4(0.f, 0.f, 0.f, 0.f);
    int s0 = 0;
    #pragma unroll
    for (int li = 0; li < 4; ++li) {
        const int Wl = 96 >> li;
        #pragma unroll
        for (int p = 0; p < NP_; ++p) {
            float ox = offp[(li * NP_ + p) * 2 + 0];
            float oy = offp[(li * NP_ + p) * 2 + 1];
            float xf = (refx + ox * (1.f / 60.f)) * Wl - 0.5f;
            float yf = (refy + oy * (1.f / 60.f)) * Wl - 0.5f;
            float x0f = floorf(xf), y0f = floorf(yf);
            float wx = xf - x0f, wy = yf - y0f;
            int x0 = (int)x0f, y0 = (int)y0f;
            float a = lv[li * NP_ + p] * sinv;
            #pragma unroll
            for (int dy = 0; dy < 2; ++dy) {
                #pragma unroll
                for (int dx = 0; dx < 2; ++dx) {
                    int yi = y0 + dy, xi = x0 + dx;
                    if (xi >= 0 && xi < Wl && yi >= 0 && yi < Wl) {
                        float wgt = a * (dy ? wy : 1.f - wy) * (dx ? wx : 1.f - wx);
                        float4 v = *(const float4*)(vbase + (size_t)(s0 + yi * Wl + xi) * C_);
                        acc.x += wgt * v.x; acc.y += wgt * v.y;
                        acc.z += wgt * v.z; acc.w += wgt * v.w;
                    }
                }
            }
        }
        s0 += Wl * Wl;
    }
    size_t ob = (size_t)gid * HD_ + q4 * 4;
    float a4[4] = {acc.x, acc.y, acc.z, acc.w};
    ushort4 hv, lv4;
    unsigned short* hp = (unsigned short*)&hv;
    unsigned short* lp = (unsigned short*)&lv4;
    #pragma unroll
    for (int j = 0; j < 4; ++j) {
        unsigned short hh = f2bf(a4[j]);
        hp[j] = hh;
        lp[j] = f2bf(a4[j] - bf2f(hh));
    }
    *(ushort4*)&msh[ob] = hv;
    *(ushort4*)&msl[ob] = lv4;
}

// ------------------------------------------------------- residual + LN ------
// v = (xh+xl) + r; LN; FINAL ? write fp32 : write split back to xh/xl
template <bool FINAL>
__global__ __launch_bounds__(256) void k_add_ln(
    unsigned short* __restrict__ xh, unsigned short* __restrict__ xl,
    const float* __restrict__ r,
    const float* __restrict__ g, const float* __restrict__ bta,
    float* __restrict__ outf)
{
    int row = blockIdx.x;
    int c = threadIdx.x;
    size_t o = (size_t)row * C_ + c;
    float v = bf2f(xh[o]) + bf2f(xl[o]) + (r ? r[o] : 0.f);
    float s1 = v, s2 = v * v;
    #pragma unroll
    for (int ofs = 32; ofs > 0; ofs >>= 1) {
        s1 += __shfl_down(s1, ofs);
        s2 += __shfl_down(s2, ofs);
    }
    __shared__ float r1[4], r2[4];
    int wid = threadIdx.x >> 6, lane = threadIdx.x & 63;
    if (lane == 0) { r1[wid] = s1; r2[wid] = s2; }
    __syncthreads();
    float m   = (r1[0] + r1[1] + r1[2] + r1[3]) * (1.f / C_);
    float var = (r2[0] + r2[1] + r2[2] + r2[3]) * (1.f / C_) - m * m;
    float inv = rsqrtf(var + 1e-5f);
    float y = (v - m) * inv * g[c] + bta[c];
    if (FINAL) {
        outf[o] = y;
    } else {
        unsigned short h = f2bf(y);
        xh[o] = h;
        xl[o] = f2bf(y - bf2f(h));
    }
}

// ---------------------------------------------------------------- launch ----
extern "C" void kernel_launch(void* const* d_in, const int* in_sizes, int n_in,
                              void* d_out, int out_size, void* d_ws, size_t ws_size,
                              hipStream_t stream)
{
    const float* src0 = (const float*)d_in[0];
    const unsigned char* mask0 = (const unsigned char*)d_in[1];
    const float* pos0 = (const float*)d_in[2];
    const float* src1 = (const float*)d_in[3];
    const unsigned char* mask1 = (const unsigned char*)d_in[4];
    const float* pos1 = (const float*)d_in[5];
    const float* src2 = (const float*)d_in[6];
    const unsigned char* mask2 = (const unsigned char*)d_in[7];
    const float* pos2 = (const float*)d_in[8];
    const float* src3 = (const float*)d_in[9];
    const unsigned char* mask3 = (const unsigned char*)d_in[10];
    const float* pos3 = (const float*)d_in[11];
    const float* lev    = (const float*)d_in[12];
    const float* W_off  = (const float*)d_in[13];
    const float* b_off  = (const float*)d_in[14];
    const float* W_attw = (const float*)d_in[15];
    const float* b_attw = (const float*)d_in[16];
    const float* W_val  = (const float*)d_in[17];
    const float* b_val  = (const float*)d_in[18];
    const float* W_out  = (const float*)d_in[19];
    const float* b_out  = (const float*)d_in[20];
    const float* ln1_g  = (const float*)d_in[21];
    const float* ln1_b  = (const float*)d_in[22];
    const float* W_ff1  = (const float*)d_in[23];
    const float* b_ff1  = (const float*)d_in[24];
    const float* W_ff2  = (const float*)d_in[25];
    const float* b_ff2  = (const float*)d_in[26];
    const float* ln2_g  = (const float*)d_in[27];
    const float* ln2_b  = (const float*)d_in[28];
    const float* lnf_g  = (const float*)d_in[29];
    const float* lnf_b  = (const float*)d_in[30];

    // ---- workspace: units of MP_ floats (1312 units + weights ~= 254 MiB)
    float* ws = (float*)d_ws;
    auto at = [&](size_t u) { return ws + u * (size_t)MP_; };
    unsigned short* xh  = (unsigned short*)at(0);     // [0,128)
    unsigned short* xl  = (unsigned short*)at(128);   // [128,256)
    float* pf   = at(256);                            // [256,512)
    float* val  = at(512);                            // [512,768)
    unsigned short* msh = (unsigned short*)at(768);   // [768,896)
    unsigned short* msl = (unsigned short*)at(896);   // [896,1024)
    float* comb = at(1024);                           // [1024,1312)
    float* tmp  = at(1024);                           // alias comb
    unsigned short* hbh = (unsigned short*)at(512);   // FFN chunk, aliases val+msda
    unsigned short* hbl = hbh + (size_t)16384 * DFF_;

    unsigned short* Wh = (unsigned short*)(ws + (size_t)1312 * MP_);
    unsigned short* Wl = Wh + (size_t)LYR_ * LT_;
    const size_t OF_VAL = 0, OF_CMB = 65536, OF_ATT = 114688,
                 OF_OUT = 139264, OF_F1 = 204800, OF_F2 = 466944;

    const dim3 T(256);
    const int BIG = 1 << 30;

    // ---- weight split+transpose
    k_split<<<(LYR_*65536 + 255)/256, T, 0, stream>>>(W_val,  Wh + OF_VAL, Wl + OF_VAL, 256, 256);
    k_split<<<(LYR_*49152 + 255)/256, T, 0, stream>>>(W_off,  Wh + OF_CMB, Wl + OF_CMB, 256, 192);
    k_split<<<(LYR_*24576 + 255)/256, T, 0, stream>>>(W_attw, Wh + OF_ATT, Wl + OF_ATT, 256, 96);
    k_split<<<(LYR_*65536 + 255)/256, T, 0, stream>>>(W_out,  Wh + OF_OUT, Wl + OF_OUT, 256, 256);
    k_split<<<(LYR_*262144 + 255)/256, T, 0, stream>>>(W_ff1, Wh + OF_F1,  Wl + OF_F1,  256, 1024);
    k_split<<<(LYR_*262144 + 255)/256, T, 0, stream>>>(W_ff2, Wh + OF_F2,  Wl + OF_F2,  1024, 256);

    k_concat_t<<<dim3(288, 8, 16), T, 0, stream>>>(
        src0, src1, src2, src3, pos0, pos1, pos2, pos3, lev, xh, xl, pf);

    for (int l = 0; l < LYR_; ++l) {
        const size_t lw = (size_t)l * LT_;

        // value = x @ W_val^T + b_val
        k_mgemm<0, 0><<<dim3(2, MP_/128), T, 0, stream>>>(
            xh, xl, nullptr, Wh + lw + OF_VAL, Wl + lw + OF_VAL,
            b_val + l*C_, b_val + l*C_, BIG, val, nullptr, nullptr, 256, 256);
        k_mask<<<M_, T, 0, stream>>>(val, mask0, mask1, mask2, mask3);

        // comb = (x+pf) @ [W_off|W_attw]^T + [b_off|b_attw]  (N = 288)
        k_mgemm<0, 1><<<dim3(3, MP_/128), T, 0, stream>>>(
            xh, xl, pf, Wh + lw + OF_CMB, Wl + lw + OF_CMB,
            b_off + l*192, b_attw + l*96, 192, comb, nullptr, nullptr, 288, 256);

        // sampling (softmax fused) -> msda split
        k_sample<<<(M_*NH_*8)/256, T, 0, stream>>>(val, comb, msh, msl);

        // out projection (into tmp; comb dead now)
        k_mgemm<0, 0><<<dim3(2, MP_/128), T, 0, stream>>>(
            msh, msl, nullptr, Wh + lw + OF_OUT, Wl + lw + OF_OUT,
            b_out + l*C_, b_out + l*C_, BIG, tmp, nullptr, nullptr, 256, 256);

        // x = LN(x + tmp)
        k_add_ln<false><<<M_, T, 0, stream>>>(xh, xl, tmp, ln1_g + l*C_, ln1_b + l*C_, nullptr);

        // FFN in 3 chunks of 16384 rows; hbuf aliases val+msda
        for (int ch = 0; ch < 3; ++ch) {
            const size_t row0 = (size_t)ch * 16384;
            k_mgemm<1, 0><<<dim3(8, 128), T, 0, stream>>>(
                xh + row0*C_, xl + row0*C_, nullptr, Wh + lw + OF_F1, Wl + lw + OF_F1,
                b_ff1 + l*DFF_, b_ff1 + l*DFF_, BIG, nullptr, hbh, hbl, 1024, 256);
            k_mgemm<0, 0><<<dim3(2, 128), T, 0, stream>>>(
                hbh, hbl, nullptr, Wh + lw + OF_F2, Wl + lw + OF_F2,
                b_ff2 + l*C_, b_ff2 + l*C_, BIG, tmp + row0*C_, nullptr, nullptr, 256, 1024);
        }

        // x = LN(x + tmp)
        k_add_ln<false><<<M_, T, 0, stream>>>(xh, xl, tmp, ln2_g + l*C_, ln2_b + l*C_, nullptr);
    }

    k_add_ln<true><<<M_, T, 0, stream>>>(xh, xl, nullptr, lnf_g, lnf_b, (float*)d_out);
}

// Round 7
// 2259.984 us; speedup vs baseline: 2.4161x; 1.0627x over previous
//
#include <hip/hip_runtime.h>

#define B_   4
#define C_   256
#define NH_  8
#define HD_  32
#define NP_  3
#define NL_  4
#define LYR_ 3
#define DFF_ 1024
#define N_   12240          // 96*96 + 48*48 + 24*24 + 12*12
#define M_   (B_*N_)        // 48960
#define MP_  49152          // rows padded to 384*128 for BM=128 tiles
#define LT_  729088         // per-layer elems in transposed weight block

typedef __attribute__((ext_vector_type(8))) short short8;
typedef __attribute__((ext_vector_type(4))) float f32x4;

__device__ __forceinline__ unsigned short f2bf(float f) {
    union { float f; unsigned u; } v; v.f = f;
    unsigned r = (v.u + 0x7fffu + ((v.u >> 16) & 1u)) >> 16;
    return (unsigned short)r;
}
__device__ __forceinline__ float bf2f(unsigned short h) {
    union { unsigned u; float f; } v; v.u = ((unsigned)h) << 16;
    return v.f;
}

// async global->LDS, 16B per lane; lds dest = wave-uniform base + lane*16
__device__ __forceinline__ void gload16(const void* g, void* lds) {
    __builtin_amdgcn_global_load_lds(
        (const __attribute__((address_space(1))) void*)g,
        (__attribute__((address_space(3))) void*)lds, 16, 0, 0);
}

// ------------------------------------------------- concat (LDS transpose) ---
__global__ __launch_bounds__(256) void k_concat_t(
    const float* __restrict__ s0, const float* __restrict__ s1,
    const float* __restrict__ s2, const float* __restrict__ s3,
    const float* __restrict__ p0, const float* __restrict__ p1,
    const float* __restrict__ p2, const float* __restrict__ p3,
    const float* __restrict__ lev,
    unsigned short* __restrict__ xh, unsigned short* __restrict__ xl,
    float* __restrict__ pf)
{
    const int z = blockIdx.z;
    const int b = z >> 2, li = z & 3;
    const int HWs[4]  = {9216, 2304, 576, 144};
    const int offs[4] = {0, 9216, 11520, 12096};
    const int HW = HWs[li];
    const int s0i = blockIdx.x * 32;
    if (s0i >= HW) return;
    const int ct = blockIdx.y * 32;
    const float* sp = (li == 0) ? s0 : (li == 1) ? s1 : (li == 2) ? s2 : s3;
    const float* pp = (li == 0) ? p0 : (li == 1) ? p1 : (li == 2) ? p2 : p3;

    __shared__ float tsx[32][33], tsp[32][33];
    const int tid = threadIdx.x;
    const int tc  = tid & 31;
    const int tr0 = tid >> 5;

    #pragma unroll
    for (int r = 0; r < 4; ++r) {
        int cl = tr0 + r * 8;
        int s  = s0i + tc;
        float vx = 0.f, vp = 0.f;
        if (s < HW) {
            size_t o = (size_t)(b * C_ + ct + cl) * HW + s;
            vx = sp[o]; vp = pp[o];
        }
        tsx[cl][tc] = vx; tsp[cl][tc] = vp;
    }
    __syncthreads();
    const float lv = lev[li * C_ + ct + tc];
    #pragma unroll
    for (int r = 0; r < 4; ++r) {
        int sl = tr0 + r * 8;
        int s  = s0i + sl;
        if (s < HW) {
            int row = b * N_ + offs[li] + s;
            size_t o = (size_t)row * C_ + ct + tc;
            float vx = tsx[tc][sl];
            unsigned short h = f2bf(vx);
            xh[o] = h;
            xl[o] = f2bf(vx - bf2f(h));
            pf[o] = tsp[tc][sl] + lv;
        }
    }
}

// ---------------------------------------------------------------- mask ------
__global__ __launch_bounds__(256) void k_mask(
    float* __restrict__ v,
    const unsigned char* __restrict__ m0, const unsigned char* __restrict__ m1,
    const unsigned char* __restrict__ m2, const unsigned char* __restrict__ m3)
{
    int row = blockIdx.x;
    int n = row % N_, b = row / N_;
    int s, HW; const unsigned char* mp;
    if (n < 9216)       { s = n;         HW = 9216; mp = m0; }
    else if (n < 11520) { s = n - 9216;  HW = 2304; mp = m1; }
    else if (n < 12096) { s = n - 11520; HW = 576;  mp = m2; }
    else                { s = n - 12096; HW = 144;  mp = m3; }
    if (mp[b * HW + s])
        v[(size_t)row * C_ + threadIdx.x] = 0.f;
}

// ------------------------------------------------------- weight split/T -----
__global__ __launch_bounds__(256) void k_split(
    const float* __restrict__ W, unsigned short* __restrict__ Th,
    unsigned short* __restrict__ Tl, int K, int N)
{
    int per = K * N;
    int idx = blockIdx.x * 256 + threadIdx.x;
    if (idx >= LYR_ * per) return;
    int l = idx / per, r = idx - l * per;
    int k = r / N, n = r - k * N;
    float v = W[idx];
    unsigned short h = f2bf(v);
    unsigned short lo = f2bf(v - bf2f(h));
    size_t o = (size_t)l * LT_ + (size_t)n * K + k;
    Th[o] = h; Tl[o] = lo;
}

// --------------------------------------------------------- MFMA GEMM --------
// C[rows][Ndim] = A[rows][K] @ T[Ndim][K]^T + bias, split-bf16 (3 MFMA).
// AKIND 0: A pre-split (Ah,Al) -> global_load_lds staging.
// AKIND 1: A = (Ah+Al) + A2f, split at stage (VALU path).
// MODE 0: fp32 store. MODE 1: exact GELU + split store.
__device__ __forceinline__ int swz(int row, int bcol) {
    return row * 128 + (bcol ^ ((row & 7) << 4));   // bytes
}

template <int MODE, int AKIND>
__global__ __launch_bounds__(256) void k_mgemm(
    const unsigned short* __restrict__ Ah, const unsigned short* __restrict__ Al,
    const float* __restrict__ A2f,
    const unsigned short* __restrict__ Bh, const unsigned short* __restrict__ Bl,
    const float* __restrict__ bias, const float* __restrict__ bias2, int bsplit,
    float* __restrict__ Cf, unsigned short* __restrict__ Ch,
    unsigned short* __restrict__ Cl, int Ndim, int Kdim)
{
    __shared__ __align__(16) unsigned short Ahs[128 * 64];
    __shared__ __align__(16) unsigned short Als[128 * 64];
    __shared__ __align__(16) unsigned short Bhs[128 * 64];
    __shared__ __align__(16) unsigned short Bls[128 * 64];

    const int tid = threadIdx.x;
    const int bm = blockIdx.y * 128;
    const int bn = blockIdx.x * 128;
    const int w  = tid >> 6, lane = tid & 63;
    const int wr = w >> 1, wc = w & 1;
    const int lm = lane & 15, lg = lane >> 4;

    // per-lane inverse-swizzled source pattern for gload staging:
    // chunk q of wave w fills LDS bytes [w*4096 + q*1024 + lane*16 .. +16)
    int grow[4], gsrc[4];
    #pragma unroll
    for (int q = 0; q < 4; ++q) {
        int o = w * 4096 + q * 1024 + lane * 16;
        int r = o >> 7;
        grow[q] = r;
        gsrc[q] = ((o & 127) ^ ((r & 7) << 4)) >> 1;   // element col in [0,64)
    }

    // VALU staging coords (AKIND 1 A-path)
    const int srow = tid >> 1;
    const int sbc  = (tid & 1) * 64;

    f32x4 acc[4][4] = {};

    for (int k0 = 0; k0 < Kdim; k0 += 64) {
        if (AKIND == 0) {   // A via global_load_lds
            #pragma unroll
            for (int q = 0; q < 4; ++q) {
                size_t go = (size_t)(bm + grow[q]) * Kdim + k0 + gsrc[q];
                char* lb = (char*)Ahs + w * 4096 + q * 1024;
                gload16(Ah + go, lb);
                gload16(Al + go, (char*)Als + w * 4096 + q * 1024);
            }
        } else {            // A = (Ah+Al)+A2f, split, ds_write
            const unsigned short* ahp = Ah + (size_t)(bm + srow) * Kdim + k0 + (sbc >> 1);
            const unsigned short* alp = Al + (size_t)(bm + srow) * Kdim + k0 + (sbc >> 1);
            const float* a2p = A2f + (size_t)(bm + srow) * Kdim + k0 + (sbc >> 1);
            #pragma unroll
            for (int q = 0; q < 4; ++q) {
                short8 h8 = *(const short8*)(ahp + q * 8);
                short8 l8 = *(const short8*)(alp + q * 8);
                float4 u0 = *(const float4*)(a2p + q * 8);
                float4 u1 = *(const float4*)(a2p + q * 8 + 4);
                float f[8] = {u0.x, u0.y, u0.z, u0.w, u1.x, u1.y, u1.z, u1.w};
                short8 hv, lv;
                #pragma unroll
                for (int j = 0; j < 8; ++j) {
                    float v = f[j] + bf2f((unsigned short)h8[j]) + bf2f((unsigned short)l8[j]);
                    unsigned short h = f2bf(v);
                    hv[j] = (short)h;
                    lv[j] = (short)f2bf(v - bf2f(h));
                }
                int o = swz(srow, sbc + q * 16) >> 1;
                *(short8*)&Ahs[o] = hv;
                *(short8*)&Als[o] = lv;
            }
        }
        {   // B via global_load_lds (clamp OOB rows; cols >= Ndim discarded)
            #pragma unroll
            for (int q = 0; q < 4; ++q) {
                int nr = bn + grow[q];
                if (nr >= Ndim) nr = Ndim - 1;
                size_t go = (size_t)nr * Kdim + k0 + gsrc[q];
                gload16(Bh + go, (char*)Bhs + w * 4096 + q * 1024);
                gload16(Bl + go, (char*)Bls + w * 4096 + q * 1024);
            }
        }
        __syncthreads();
        #pragma unroll
        for (int ks = 0; ks < 2; ++ks) {
            const int cb = ks * 64 + lg * 16;
            short8 ah[4], al[4], bh[4], bl[4];
            #pragma unroll
            for (int i = 0; i < 4; ++i) {
                int o = swz(wr * 64 + i * 16 + lm, cb) >> 1;
                ah[i] = *(const short8*)&Ahs[o];
                al[i] = *(const short8*)&Als[o];
            }
            #pragma unroll
            for (int j = 0; j < 4; ++j) {
                int o = swz(wc * 64 + j * 16 + lm, cb) >> 1;
                bh[j] = *(const short8*)&Bhs[o];
                bl[j] = *(const short8*)&Bls[o];
            }
            #pragma unroll
            for (int i = 0; i < 4; ++i)
                #pragma unroll
                for (int j = 0; j < 4; ++j) {
                    acc[i][j] = __builtin_amdgcn_mfma_f32_16x16x32_bf16(al[i], bh[j], acc[i][j], 0, 0, 0);
                    acc[i][j] = __builtin_amdgcn_mfma_f32_16x16x32_bf16(ah[i], bl[j], acc[i][j], 0, 0, 0);
                    acc[i][j] = __builtin_amdgcn_mfma_f32_16x16x32_bf16(ah[i], bh[j], acc[i][j], 0, 0, 0);
                }
        }
        __syncthreads();
    }

    // epilogue. C/D: col = lane&15, row = (lane>>4)*4 + p
    #pragma unroll
    for (int j = 0; j < 4; ++j) {
        int col = bn + wc * 64 + j * 16 + lm;
        if (col < Ndim) {
            float bb = (col < bsplit) ? bias[col] : bias2[col - bsplit];
            #pragma unroll
            for (int i = 0; i < 4; ++i) {
                #pragma unroll
                for (int p = 0; p < 4; ++p) {
                    int row = bm + wr * 64 + i * 16 + lg * 4 + p;
                    float v = acc[i][j][p] + bb;
                    if (MODE == 1) {
                        v = 0.5f * v * (1.f + erff(v * 0.70710678118654752f));
                        unsigned short h = f2bf(v);
                        Ch[(size_t)row * Ndim + col] = h;
                        Cl[(size_t)row * Ndim + col] = f2bf(v - bf2f(h));
                    } else {
                        Cf[(size_t)row * Ndim + col] = v;
                    }
                }
            }
        }
    }
}

// -------------------------------------------------------------- sampling ----
// 8 lanes per (b,n,h); softmax over 12 fused; XCD-chunked block swizzle.
__global__ __launch_bounds__(256) void k_sample(
    const float* __restrict__ value, const float* __restrict__ comb,
    unsigned short* __restrict__ msh, unsigned short* __restrict__ msl)
{
    const int nwg = (M_ * NH_ * 8) / 256;          // 12240, % 8 == 0
    const int cpx = nwg >> 3;
    int bid = blockIdx.x;
    int sb  = (bid & 7) * cpx + (bid >> 3);        // bijective XCD chunking
    int t   = sb * 256 + threadIdx.x;
    int gid = t >> 3;
    int q4  = t & 7;
    int h  = gid & 7;
    int bn = gid >> 3;
    int n  = bn % N_;
    int b  = bn / N_;

    int sr, Wr;
    if (n < 9216)       { sr = n;         Wr = 96; }
    else if (n < 11520) { sr = n - 9216;  Wr = 48; }
    else if (n < 12096) { sr = n - 11520; Wr = 24; }
    else                { sr = n - 12096; Wr = 12; }
    int iy = sr / Wr, ix = sr % Wr;
    float refx = (ix + 0.5f) / Wr;
    float refy = (iy + 0.5f) / Wr;

    const float* rowp = comb + (size_t)bn * 288;
    const float* offp = rowp + h * 24;
    const float* lgp  = rowp + 192 + h * 12;

    float lv[12];
    float mx = lgp[0];
    lv[0] = mx;
    #pragma unroll
    for (int i = 1; i < 12; ++i) { lv[i] = lgp[i]; mx = fmaxf(mx, lv[i]); }
    float ssum = 0.f;
    #pragma unroll
    for (int i = 0; i < 12; ++i) { lv[i] = __expf(lv[i] - mx); ssum += lv[i]; }
    float sinv = 1.f / ssum;

    const float* vbase = value + ((size_t)b * N_) * C_ + h * HD_ + q4 * 4;

    float4 acc = make_float4(0.f, 0.f, 0.f, 0.f);
    int s0 = 0;
    #pragma unroll
    for (int li = 0; li < 4; ++li) {
        const int Wl = 96 >> li;
        #pragma unroll
        for (int p = 0; p < NP_; ++p) {
            float ox = offp[(li * NP_ + p) * 2 + 0];
            float oy = offp[(li * NP_ + p) * 2 + 1];
            float xf = (refx + ox * (1.f / 60.f)) * Wl - 0.5f;
            float yf = (refy + oy * (1.f / 60.f)) * Wl - 0.5f;
            float x0f = floorf(xf), y0f = floorf(yf);
            float wx = xf - x0f, wy = yf - y0f;
            int x0 = (int)x0f, y0 = (int)y0f;
            float a = lv[li * NP_ + p] * sinv;
            #pragma unroll
            for (int dy = 0; dy < 2; ++dy) {
                #pragma unroll
                for (int dx = 0; dx < 2; ++dx) {
                    int yi = y0 + dy, xi = x0 + dx;
                    if (xi >= 0 && xi < Wl && yi >= 0 && yi < Wl) {
                        float wgt = a * (dy ? wy : 1.f - wy) * (dx ? wx : 1.f - wx);
                        float4 v = *(const float4*)(vbase + (size_t)(s0 + yi * Wl + xi) * C_);
                        acc.x += wgt * v.x; acc.y += wgt * v.y;
                        acc.z += wgt * v.z; acc.w += wgt * v.w;
                    }
                }
            }
        }
        s0 += Wl * Wl;
    }
    size_t ob = (size_t)gid * HD_ + q4 * 4;
    float a4[4] = {acc.x, acc.y, acc.z, acc.w};
    ushort4 hv, lv4;
    unsigned short* hp = (unsigned short*)&hv;
    unsigned short* lp = (unsigned short*)&lv4;
    #pragma unroll
    for (int j = 0; j < 4; ++j) {
        unsigned short hh = f2bf(a4[j]);
        hp[j] = hh;
        lp[j] = f2bf(a4[j] - bf2f(hh));
    }
    *(ushort4*)&msh[ob] = hv;
    *(ushort4*)&msl[ob] = lv4;
}

// ------------------------------------------------------- residual + LN ------
template <bool FINAL>
__global__ __launch_bounds__(256) void k_add_ln(
    unsigned short* __restrict__ xh, unsigned short* __restrict__ xl,
    const float* __restrict__ r,
    const float* __restrict__ g, const float* __restrict__ bta,
    float* __restrict__ outf)
{
    int row = blockIdx.x;
    int c = threadIdx.x;
    size_t o = (size_t)row * C_ + c;
    float v = bf2f(xh[o]) + bf2f(xl[o]) + (r ? r[o] : 0.f);
    float s1 = v, s2 = v * v;
    #pragma unroll
    for (int ofs = 32; ofs > 0; ofs >>= 1) {
        s1 += __shfl_down(s1, ofs);
        s2 += __shfl_down(s2, ofs);
    }
    __shared__ float r1[4], r2[4];
    int wid = threadIdx.x >> 6, lane = threadIdx.x & 63;
    if (lane == 0) { r1[wid] = s1; r2[wid] = s2; }
    __syncthreads();
    float m   = (r1[0] + r1[1] + r1[2] + r1[3]) * (1.f / C_);
    float var = (r2[0] + r2[1] + r2[2] + r2[3]) * (1.f / C_) - m * m;
    float inv = rsqrtf(var + 1e-5f);
    float y = (v - m) * inv * g[c] + bta[c];
    if (FINAL) {
        outf[o] = y;
    } else {
        unsigned short h = f2bf(y);
        xh[o] = h;
        xl[o] = f2bf(y - bf2f(h));
    }
}

// ---------------------------------------------------------------- launch ----
extern "C" void kernel_launch(void* const* d_in, const int* in_sizes, int n_in,
                              void* d_out, int out_size, void* d_ws, size_t ws_size,
                              hipStream_t stream)
{
    const float* src0 = (const float*)d_in[0];
    const unsigned char* mask0 = (const unsigned char*)d_in[1];
    const float* pos0 = (const float*)d_in[2];
    const float* src1 = (const float*)d_in[3];
    const unsigned char* mask1 = (const unsigned char*)d_in[4];
    const float* pos1 = (const float*)d_in[5];
    const float* src2 = (const float*)d_in[6];
    const unsigned char* mask2 = (const unsigned char*)d_in[7];
    const float* pos2 = (const float*)d_in[8];
    const float* src3 = (const float*)d_in[9];
    const unsigned char* mask3 = (const unsigned char*)d_in[10];
    const float* pos3 = (const float*)d_in[11];
    const float* lev    = (const float*)d_in[12];
    const float* W_off  = (const float*)d_in[13];
    const float* b_off  = (const float*)d_in[14];
    const float* W_attw = (const float*)d_in[15];
    const float* b_attw = (const float*)d_in[16];
    const float* W_val  = (const float*)d_in[17];
    const float* b_val  = (const float*)d_in[18];
    const float* W_out  = (const float*)d_in[19];
    const float* b_out  = (const float*)d_in[20];
    const float* ln1_g  = (const float*)d_in[21];
    const float* ln1_b  = (const float*)d_in[22];
    const float* W_ff1  = (const float*)d_in[23];
    const float* b_ff1  = (const float*)d_in[24];
    const float* W_ff2  = (const float*)d_in[25];
    const float* b_ff2  = (const float*)d_in[26];
    const float* ln2_g  = (const float*)d_in[27];
    const float* ln2_b  = (const float*)d_in[28];
    const float* lnf_g  = (const float*)d_in[29];
    const float* lnf_b  = (const float*)d_in[30];

    float* ws = (float*)d_ws;
    auto at = [&](size_t u) { return ws + u * (size_t)MP_; };
    unsigned short* xh  = (unsigned short*)at(0);
    unsigned short* xl  = (unsigned short*)at(128);
    float* pf   = at(256);
    float* val  = at(512);
    unsigned short* msh = (unsigned short*)at(768);
    unsigned short* msl = (unsigned short*)at(896);
    float* comb = at(1024);
    float* tmp  = at(1024);
    unsigned short* hbh = (unsigned short*)at(512);
    unsigned short* hbl = hbh + (size_t)16384 * DFF_;

    unsigned short* Wh = (unsigned short*)(ws + (size_t)1312 * MP_);
    unsigned short* Wl = Wh + (size_t)LYR_ * LT_;
    const size_t OF_VAL = 0, OF_CMB = 65536, OF_ATT = 114688,
                 OF_OUT = 139264, OF_F1 = 204800, OF_F2 = 466944;

    const dim3 T(256);
    const int BIG = 1 << 30;

    k_split<<<(LYR_*65536 + 255)/256, T, 0, stream>>>(W_val,  Wh + OF_VAL, Wl + OF_VAL, 256, 256);
    k_split<<<(LYR_*49152 + 255)/256, T, 0, stream>>>(W_off,  Wh + OF_CMB, Wl + OF_CMB, 256, 192);
    k_split<<<(LYR_*24576 + 255)/256, T, 0, stream>>>(W_attw, Wh + OF_ATT, Wl + OF_ATT, 256, 96);
    k_split<<<(LYR_*65536 + 255)/256, T, 0, stream>>>(W_out,  Wh + OF_OUT, Wl + OF_OUT, 256, 256);
    k_split<<<(LYR_*262144 + 255)/256, T, 0, stream>>>(W_ff1, Wh + OF_F1,  Wl + OF_F1,  256, 1024);
    k_split<<<(LYR_*262144 + 255)/256, T, 0, stream>>>(W_ff2, Wh + OF_F2,  Wl + OF_F2,  1024, 256);

    k_concat_t<<<dim3(288, 8, 16), T, 0, stream>>>(
        src0, src1, src2, src3, pos0, pos1, pos2, pos3, lev, xh, xl, pf);

    for (int l = 0; l < LYR_; ++l) {
        const size_t lw = (size_t)l * LT_;

        // value = x @ W_val^T + b_val
        k_mgemm<0, 0><<<dim3(2, MP_/128), T, 0, stream>>>(
            xh, xl, nullptr, Wh + lw + OF_VAL, Wl + lw + OF_VAL,
            b_val + l*C_, b_val + l*C_, BIG, val, nullptr, nullptr, 256, 256);
        k_mask<<<M_, T, 0, stream>>>(val, mask0, mask1, mask2, mask3);

        // comb = (x+pf) @ [W_off|W_attw]^T + [b_off|b_attw]  (N = 288)
        k_mgemm<0, 1><<<dim3(3, MP_/128), T, 0, stream>>>(
            xh, xl, pf, Wh + lw + OF_CMB, Wl + lw + OF_CMB,
            b_off + l*192, b_attw + l*96, 192, comb, nullptr, nullptr, 288, 256);

        // sampling (softmax fused) -> msda split
        k_sample<<<(M_*NH_*8)/256, T, 0, stream>>>(val, comb, msh, msl);

        // out projection (into tmp; comb dead now)
        k_mgemm<0, 0><<<dim3(2, MP_/128), T, 0, stream>>>(
            msh, msl, nullptr, Wh + lw + OF_OUT, Wl + lw + OF_OUT,
            b_out + l*C_, b_out + l*C_, BIG, tmp, nullptr, nullptr, 256, 256);

        // x = LN(x + tmp)
        k_add_ln<false><<<M_, T, 0, stream>>>(xh, xl, tmp, ln1_g + l*C_, ln1_b + l*C_, nullptr);

        // FFN in 3 chunks of 16384 rows; hbuf aliases val+msda
        for (int ch = 0; ch < 3; ++ch) {
            const size_t row0 = (size_t)ch * 16384;
            k_mgemm<1, 0><<<dim3(8, 128), T, 0, stream>>>(
                xh + row0*C_, xl + row0*C_, nullptr, Wh + lw + OF_F1, Wl + lw + OF_F1,
                b_ff1 + l*DFF_, b_ff1 + l*DFF_, BIG, nullptr, hbh, hbl, 1024, 256);
            k_mgemm<0, 0><<<dim3(2, 128), T, 0, stream>>>(
                hbh, hbl, nullptr, Wh + lw + OF_F2, Wl + lw + OF_F2,
                b_ff2 + l*C_, b_ff2 + l*C_, BIG, tmp + row0*C_, nullptr, nullptr, 256, 1024);
        }

        // x = LN(x + tmp)
        k_add_ln<false><<<M_, T, 0, stream>>>(xh, xl, tmp, ln2_g + l*C_, ln2_b + l*C_, nullptr);
    }

    k_add_ln<true><<<M_, T, 0, stream>>>(xh, xl, nullptr, lnf_g, lnf_b, (float*)d_out);
}